// Round 2
// baseline (180.228 us; speedup 1.0000x reference)
//
#include <hip/hip_runtime.h>
#include <hip/hip_bf16.h>

// DynamicConv1D: out[b,t,f] = sum_{k,d} xp[b,t+k,d] * kernels[b,t,k,f]
// Factorizes: out[b,t,f] = sum_k S[b,t+k-1] * kernels[b,t,k,f],
// where S[b,u] = sum_d x[b,u,d], S out-of-range = 0.
// B=8, T=2048, D=512, K=3, F=512. fp32. Memory-bound: ~142 MB read + 34 MB
// write -> ~26 us at 6.9 TB/s achieved fill BW.
//
// Fused single kernel: block = 256 threads handles TT=8 consecutive t of one
// batch row. Phase 1: 10 row sums (t-1..t+8) -> LDS. Phase 2: 3-tap combine.
// All global loads (6 x-float4 + 12 kern-float4 per thread) are issued before
// any use, so the shuffle-reduce + barrier overlap the in-flight kern loads.

#define B_ 8
#define T_ 2048
#define D_ 512
#define F_ 512
#define TT 8               // t-values per block
#define NROWS (TT + 2)     // row sums needed per block

__global__ __launch_bounds__(256) void fused_conv_kernel(
    const float* __restrict__ x, const float* __restrict__ kern,
    float* __restrict__ out) {
    __shared__ float Ss[NROWS];

    const int tid  = threadIdx.x;
    const int wave = tid >> 6;
    const int lane = tid & 63;
    const int bt0  = blockIdx.x * TT;       // first (b,t) flat row
    const int t0   = bt0 & (T_ - 1);        // first t within batch (T pow2)

    // ---------- Phase 1 loads: row sums rows t0-1 .. t0+TT ----------
    // wave w handles rows w, w+4, w+8 (waves 0,1: 3 rows; waves 2,3: 2 rows)
    float4 va[3], vb[3];
    #pragma unroll
    for (int i = 0; i < 3; ++i) {
        const int r  = wave + i * 4;
        const int gt = t0 + r - 1;
        va[i] = make_float4(0.f, 0.f, 0.f, 0.f);
        vb[i] = make_float4(0.f, 0.f, 0.f, 0.f);
        if (r < NROWS && gt >= 0 && gt < T_) {
            const float4* xr = (const float4*)(x + (size_t)(bt0 + r - 1) * D_);
            va[i] = xr[lane];               // D/4 = 128 float4; 64 lanes x 2
            vb[i] = xr[lane + 64];
        }
    }

    // ---------- Phase 2 loads: kernels (independent of S) ----------
    // work grid: 4 iters x (t_local = it*2 + tid>>7, f4 = tid&127)
    const int f4  = tid & 127;
    const int tl0 = tid >> 7;               // 0 or 1
    float4 kk[4][3];
    #pragma unroll
    for (int it = 0; it < 4; ++it) {
        const int tl = it * 2 + tl0;
        const float4* kr = (const float4*)(kern + (size_t)(bt0 + tl) * (3 * F_));
        kk[it][0] = kr[f4];                 // k = 0 plane
        kk[it][1] = kr[f4 + 128];           // k = 1 plane
        kk[it][2] = kr[f4 + 256];           // k = 2 plane
    }

    // ---------- Phase 1 reduce (waits only on x loads; kern stays in flight)
    #pragma unroll
    for (int i = 0; i < 3; ++i) {
        const int r = wave + i * 4;
        if (r < NROWS) {
            float s = (va[i].x + va[i].y) + (va[i].z + va[i].w)
                    + (vb[i].x + vb[i].y) + (vb[i].z + vb[i].w);
            #pragma unroll
            for (int off = 32; off > 0; off >>= 1)
                s += __shfl_down(s, off, 64);
            if (lane == 0) Ss[r] = s;
        }
    }
    __syncthreads();

    // ---------- Phase 2 compute + store ----------
    #pragma unroll
    for (int it = 0; it < 4; ++it) {
        const int tl = it * 2 + tl0;
        const float s0 = Ss[tl];            // wave-uniform -> LDS broadcast
        const float s1 = Ss[tl + 1];
        const float s2 = Ss[tl + 2];
        float4 o;
        o.x = s0 * kk[it][0].x + s1 * kk[it][1].x + s2 * kk[it][2].x;
        o.y = s0 * kk[it][0].y + s1 * kk[it][1].y + s2 * kk[it][2].y;
        o.z = s0 * kk[it][0].z + s1 * kk[it][1].z + s2 * kk[it][2].z;
        o.w = s0 * kk[it][0].w + s1 * kk[it][1].w + s2 * kk[it][2].w;
        ((float4*)(out + (size_t)(bt0 + tl) * F_))[f4] = o;
    }
}

extern "C" void kernel_launch(void* const* d_in, const int* in_sizes, int n_in,
                              void* d_out, int out_size, void* d_ws, size_t ws_size,
                              hipStream_t stream) {
    const float* x    = (const float*)d_in[0];   // [B, T, D]
    const float* kern = (const float*)d_in[1];   // [B, T, K, F]
    float* out = (float*)d_out;                  // [B, T, F]

    const int blocks = (B_ * T_) / TT;           // 2048
    fused_conv_kernel<<<blocks, 256, 0, stream>>>(x, kern, out);
}